// Round 4
// baseline (577.970 us; speedup 1.0000x reference)
//
#include <hip/hip_runtime.h>

typedef __bf16 bf16x8 __attribute__((ext_vector_type(8)));
typedef float  floatx4 __attribute__((ext_vector_type(4)));

constexpr int B_    = 2048;
constexpr int NIN   = 256;
constexpr int H_    = 128;
constexpr int RANK_ = 8;
constexpr float EPS_ = 1e-5f;
constexpr int NBLK = 256;

// Monotonic-counter grid barrier. Safe: 256 blocks x 256 thr, 35.8KB LDS,
// guarantees 1 block/CU co-residency on 256 CUs. Device-scope fence + atomics.
__device__ __forceinline__ void gsync(unsigned* cnt, unsigned target) {
    __syncthreads();
    if (threadIdx.x == 0) {
        __threadfence();
        atomicAdd(cnt, 1u);
        while (__hip_atomic_load(cnt, __ATOMIC_ACQUIRE, __HIP_MEMORY_SCOPE_AGENT) < target)
            __builtin_amdgcn_s_sleep(2);
        __threadfence();
    }
    __syncthreads();
}

__global__ __launch_bounds__(256)
void k_mega(const float* __restrict__ X,  const float* __restrict__ W1, const float* __restrict__ b1,
            const float* __restrict__ W2, const float* __restrict__ b2,
            const float* __restrict__ W3, const float* __restrict__ b3,
            const float* __restrict__ P,  const float* __restrict__ gz, const float* __restrict__ bz,
            const float* __restrict__ gy, const float* __restrict__ by,
            float* __restrict__ out, unsigned* __restrict__ cnt,
            float* __restrict__ Z, float* __restrict__ R2, float* __restrict__ Y,
            float* __restrict__ sums, float* __restrict__ ysums,
            float* __restrict__ T, __bf16* __restrict__ Zbf, __bf16* __restrict__ Pperm)
{
    __shared__ float smem[8960];          // 35840 B: sZin[128][68] + alpha/beta tail
    const int bx = blockIdx.x, t = threadIdx.x;
    unsigned btgt = 0;

    // ================= phase 0: zero stats, in_proj, pconv =================
    if (bx < RANK_)       sums[bx * 256 + t] = 0.f;
    else if (bx == RANK_) ysums[t & 255] = 0.f;

    {   // in_proj: rows bx*8 .. +8 ; Z=relu(XW1+b1), R2=relu(XW2+b2), Zbf=bf16(Z)
        const int col = t & 127, half = t >> 7;
        for (int it = 0; it < 4; ++it) {
            const int row0 = bx * 8 + it * 2;
            smem[t]       = X[(size_t)row0       * NIN + t];
            smem[256 + t] = X[(size_t)(row0 + 1) * NIN + t];
            __syncthreads();
            float s1 = 0.f, s2 = 0.f;
            const float* sx = smem + half * 256;
#pragma unroll 8
            for (int i = 0; i < NIN; ++i) {
                s1 = fmaf(sx[i], W1[i * H_ + col], s1);
                s2 = fmaf(sx[i], W2[i * H_ + col], s2);
            }
            const int b = row0 + half;
            const float z = fmaxf(s1 + b1[col], 0.f);
            const float r = fmaxf(s2 + b2[col], 0.f);
            Z[(size_t)b * H_ + col]   = z;
            Zbf[(size_t)b * H_ + col] = (__bf16)z;
            R2[(size_t)b * H_ + col]  = r;
            __syncthreads();
        }
    }
    {   // pconv: units bx*4 .. +4 (1024 = 8 ranks x 128 p); B-frag order
        const int s = t >> 6, L = t & 63, quad = L >> 4, lo = L & 15;
        for (int j = 0; j < 4; ++j) {
            const int u = bx * 4 + j, pr = u >> 7, p = u & 127;
            const float* Pp = P     + ((size_t)pr * H_ + p) * (H_ * H_);
            __bf16*      dp = Pperm + ((size_t)pr * H_ + p) * (H_ * H_);
#pragma unroll
            for (int c = 0; c < 8; ++c) {
                __bf16 v[8];
#pragma unroll
                for (int jj = 0; jj < 8; ++jj)
                    v[jj] = (__bf16)Pp[(s * 32 + quad * 8 + jj) * H_ + c * 16 + lo];
                *(bf16x8*)(dp + (((size_t)(s * 8 + c)) * 64 + L) * 8) = *(const bf16x8*)v;
            }
        }
    }
    btgt += NBLK; gsync(cnt, btgt);

    // ================= rank loop: quad with fused BN-on-read =================
    const int m  = bx >> 3, kg = bx & 7;       // kg == bx%8 -> XCD-aligned B slice
    const int b0 = m * 64;
    const int w = t >> 6, L = t & 63, quad = L >> 4, lo = L & 15;

    for (int r = 0; r < RANK_; ++r) {
        // alpha/beta for previous rank's BN (identity for r==0)
        float* sAl = smem + 8704; float* sBe = smem + 8832;
        if (t < 128) {
            if (r == 0) { sAl[t] = 1.f; sBe[t] = 0.f; }
            else {
                const float s1 = sums[(r-1)*256 + t], s2 = sums[(r-1)*256 + 128 + t];
                const float mm = s1 * (1.f / B_);
                const float var = s2 * (1.f / B_) - mm * mm;
                const float a = rsqrtf(var + EPS_) * gz[t];
                sAl[t] = a; sBe[t] = bz[t] - mm * a;
            }
        }
        __syncthreads();
        // stage normalized Zi tile: sZin[p][row], stride 68 (bank-safe b128 reads)
        {
            const float* prevT = (r == 0) ? Z : (T + (size_t)(r-1) * B_ * H_);
            const int p = t & 127, rg = t >> 7;
            const float a = sAl[p], be = sBe[p];
            for (int it = 0; it < 8; ++it) {
                const int row0 = (rg + it * 2) * 4;
                float4 v;
                v.x = prevT[(size_t)(b0 + row0 + 0) * H_ + p];
                v.y = prevT[(size_t)(b0 + row0 + 1) * H_ + p];
                v.z = prevT[(size_t)(b0 + row0 + 2) * H_ + p];
                v.w = prevT[(size_t)(b0 + row0 + 3) * H_ + p];
                v.x = fmaf(v.x, a, be); v.y = fmaf(v.y, a, be);
                v.z = fmaf(v.z, a, be); v.w = fmaf(v.w, a, be);
                *(float4*)&smem[p * 68 + row0] = v;
            }
        }
        // A-frags: Z rows (rank-invariant), 64 rows x K=128
        bf16x8 A[4][4];
#pragma unroll
        for (int mt = 0; mt < 4; ++mt)
#pragma unroll
            for (int ks = 0; ks < 4; ++ks)
                A[mt][ks] = *(const bf16x8*)(Zbf + (size_t)(b0 + mt*16 + lo) * H_ + ks*32 + quad*8);
        __syncthreads();

        floatx4 acc[4];
#pragma unroll
        for (int mt = 0; mt < 4; ++mt) acc[mt] = (floatx4){0.f, 0.f, 0.f, 0.f};

        const bf16x8* Pb = (const bf16x8*)(Pperm + (size_t)r * H_ * H_ * H_);
        for (int pp = 0; pp < 32; ++pp) {
            const int p = pp * 4 + w;          // wave-strided p split
            bf16x8 Bf[4];
#pragma unroll
            for (int s = 0; s < 4; ++s)
                Bf[s] = Pb[((size_t)(p * 4 + s) * 8 + kg) * 64 + L];
            floatx4 S[4];
#pragma unroll
            for (int mt = 0; mt < 4; ++mt) S[mt] = (floatx4){0.f, 0.f, 0.f, 0.f};
#pragma unroll
            for (int ks = 0; ks < 4; ++ks)
#pragma unroll
                for (int mt = 0; mt < 4; ++mt)
                    S[mt] = __builtin_amdgcn_mfma_f32_16x16x32_bf16(A[mt][ks], Bf[ks], S[mt], 0, 0, 0);
#pragma unroll
            for (int mt = 0; mt < 4; ++mt) {
                const floatx4 zi = *(const floatx4*)&smem[p * 68 + mt * 16 + quad * 4];
                acc[mt] += zi * S[mt];
            }
        }
        __syncthreads();                       // sZin dead; reuse smem for reduce
        // cross-wave p-reduction
#pragma unroll
        for (int mt = 0; mt < 4; ++mt)
#pragma unroll
            for (int i = 0; i < 4; ++i)
                smem[w * 1024 + (mt * 4 + i) * 64 + L] = acc[mt][i];
        if (t < 32) smem[4096 + t] = 0.f;      // col sum / sumsq accumulators
        __syncthreads();
        float* Tr = T + (size_t)r * B_ * H_;
        float cs = 0.f, cs2 = 0.f;
#pragma unroll
        for (int k = 0; k < 4; ++k) {
            const int e = t + 256 * k;
            const float v = smem[e] + smem[1024 + e] + smem[2048 + e] + smem[3072 + e];
            const int row = b0 + k * 16 + ((t & 63) >> 4) * 4 + (t >> 6);
            const int col = kg * 16 + (t & 15);
            Tr[(size_t)row * H_ + col] = v;
            cs += v; cs2 += v * v;
        }
        atomicAdd(&smem[4096 + (t & 15)], cs);
        atomicAdd(&smem[4112 + (t & 15)], cs2);
        __syncthreads();
        if (t < 16) {
            atomicAdd(&sums[r * 256 + kg * 16 + t],       smem[4096 + t]);
            atomicAdd(&sums[r * 256 + 128 + kg * 16 + t], smem[4112 + t]);
        }
        btgt += NBLK; gsync(cnt, btgt);
    }

    // ================= F1: Y = (1/8) sum_r bn_r(T_r); ystats =================
    {
        float* al = smem; float* be = smem + 1024;
        for (int e = t; e < 1024; e += 256) {
            const int rr = e >> 7, k = e & 127;
            const float s1 = sums[rr * 256 + k], s2 = sums[rr * 256 + 128 + k];
            const float mm = s1 * (1.f / B_);
            const float var = s2 * (1.f / B_) - mm * mm;
            const float a = rsqrtf(var + EPS_) * gz[k];
            al[e] = a; be[e] = bz[k] - mm * a;
        }
        if (t < 128) { smem[2048 + t] = 0.f; smem[2176 + t] = 0.f; }
        __syncthreads();
        const int col = t & 127, half = t >> 7;
        float ps = 0.f, ps2 = 0.f;
        for (int i = 0; i < 4; ++i) {
            const int b = bx * 8 + i * 2 + half;
            float y = 0.f;
#pragma unroll
            for (int rr = 0; rr < 8; ++rr)
                y += fmaf(T[(size_t)rr * B_ * H_ + (size_t)b * H_ + col],
                          al[rr * 128 + col], be[rr * 128 + col]);
            y *= (1.f / RANK_);
            Y[(size_t)b * H_ + col] = y;
            ps += y; ps2 += y * y;
        }
        atomicAdd(&smem[2048 + col], ps);
        atomicAdd(&smem[2176 + col], ps2);
        __syncthreads();
        if (t < 128) {
            atomicAdd(&ysums[t],       smem[2048 + t]);
            atomicAdd(&ysums[128 + t], smem[2176 + t]);
        }
    }
    btgt += NBLK; gsync(cnt, btgt);

    // ================= F2: out = relu(relu(BN(Y)@W3+b3) + R2) =================
    {
        const int col = t & 127, half = t >> 7;
        const float mm = ysums[col] * (1.f / B_);
        const float var = ysums[128 + col] * (1.f / B_) - mm * mm;
        const float a = rsqrtf(var + EPS_) * gy[col];
        const float bb = by[col] - mm * a;
        for (int i = 0; i < 4; ++i) {
            const int b = bx * 8 + i * 2 + half;
            smem[half * 128 + col] = fmaf(Y[(size_t)b * H_ + col], a, bb);
            __syncthreads();
            float s = 0.f;
            const float* sy = smem + half * 128;
#pragma unroll 8
            for (int h = 0; h < H_; ++h)
                s = fmaf(sy[h], W3[h * H_ + col], s);
            const float res = fmaxf(s + b3[col], 0.f) + R2[(size_t)b * H_ + col];
            out[(size_t)b * H_ + col] = fmaxf(res, 0.f);
            __syncthreads();
        }
    }
}

// ---------------------------------------------------------------------------
extern "C" void kernel_launch(void* const* d_in, const int* in_sizes, int n_in,
                              void* d_out, int out_size, void* d_ws, size_t ws_size,
                              hipStream_t stream) {
    const float* X  = (const float*)d_in[0];
    const float* W1 = (const float*)d_in[1];
    const float* b1 = (const float*)d_in[2];
    const float* W2 = (const float*)d_in[3];
    const float* b2 = (const float*)d_in[4];
    const float* W3 = (const float*)d_in[5];
    const float* b3 = (const float*)d_in[6];
    const float* P  = (const float*)d_in[7];
    const float* gz = (const float*)d_in[8];
    const float* bz = (const float*)d_in[9];
    const float* gy = (const float*)d_in[10];
    const float* by = (const float*)d_in[11];
    float* out = (float*)d_out;

    char* wsb = (char*)d_ws;
    unsigned* cnt = (unsigned*)wsb;                 wsb += 256;
    float* Z      = (float*)wsb;                    wsb += (size_t)B_ * H_ * 4;
    float* R2     = (float*)wsb;                    wsb += (size_t)B_ * H_ * 4;
    float* Y      = (float*)wsb;                    wsb += (size_t)B_ * H_ * 4;
    float* sums   = (float*)wsb;                    wsb += (size_t)RANK_ * 256 * 4;
    float* ysums  = (float*)wsb;                    wsb += 256 * 4;
    float* T      = (float*)wsb;                    wsb += (size_t)RANK_ * B_ * H_ * 4;
    __bf16* Zbf   = (__bf16*)wsb;                   wsb += (size_t)B_ * H_ * 2;
    __bf16* Pperm = (__bf16*)wsb;

    hipMemsetAsync(cnt, 0, 256, stream);
    k_mega<<<NBLK, 256, 0, stream>>>(X, W1, b1, W2, b2, W3, b3, P, gz, bz, gy, by,
                                     out, cnt, Z, R2, Y, sums, ysums, T, Zbf, Pperm);
}